// Round 2
// baseline (635.971 us; speedup 1.0000x reference)
//
#include <hip/hip_runtime.h>

#define DD   256
#define TT   1024
#define BB   8
#define BT   8192
#define KK   8192
#define SPLITS 16
#define NSPLIT 512          // codes per split
#define TILE_M 128          // tokens per block
#define TILE_N 256          // codes per inner tile
#define CT     2            // NSPLIT / TILE_N
#define KC     32           // d-chunk
#define NKC    8            // DD / KC
#define CS_W   288          // swizzled Cs row width (256 + 32 gap floats)

#define ZQ_SIZE 2097152     // B*D*T

// ws layout in floats
#define CBT_OFF  0
#define A_OFF    2097152
#define C_OFF    (A_OFF + BT)
#define VAL_OFF  (C_OFF + KK)
#define IDX_OFF  (VAL_OFF + SPLITS*BT)
#define FIDX_OFF (IDX_OFF + SPLITS*BT)
#define ACC_OFF  (FIDX_OFF + BT)

#define FLT_INF 3.402823466e38f

// ---------------- kernel 1: prep = token norms + codebook transpose + code norms ----------------
__global__ __launch_bounds__(256) void vq_prep(const float* __restrict__ z,
                                               const float* __restrict__ cb,
                                               float* __restrict__ An,
                                               float* __restrict__ CbT,
                                               float* __restrict__ Cn) {
    if (blockIdx.x < 32) {
        // A[token] = sum_d z[b,d,t]^2 ; coalesced over t
        int g = blockIdx.x * 256 + threadIdx.x;      // 0..8191
        int b = g >> 10, t = g & 1023;
        const float* zp = z + (size_t)b * (DD * TT) + t;
        float s = 0.f;
        #pragma unroll 8
        for (int d = 0; d < DD; ++d) {
            float v = zp[d * TT];
            float v2 = v * v;              // match np: square rounded, then sum
            s = s + v2;
        }
        An[g] = s;
    } else if (blockIdx.x < 32 + 2048) {
        // transpose codebook: CbT[d][code] = cb[code][d]
        int fid = (blockIdx.x - 32) * 256 + threadIdx.x;   // 0..524287
        int code = fid & 8191;
        int d = (fid >> 13) * 4;                           // 0..252
        float4 v = *(const float4*)&cb[(size_t)code * DD + d];
        CbT[(size_t)(d + 0) * KK + code] = v.x;            // coalesced over code
        CbT[(size_t)(d + 1) * KK + code] = v.y;
        CbT[(size_t)(d + 2) * KK + code] = v.z;
        CbT[(size_t)(d + 3) * KK + code] = v.w;
    } else {
        // C[code] = ||codebook row||^2, one wave per code
        int code = (blockIdx.x - 2080) * 4 + (threadIdx.x >> 6);
        int lane = threadIdx.x & 63;
        float4 v = *(const float4*)&cb[(size_t)code * DD + lane * 4];
        float s = v.x * v.x + v.y * v.y + v.z * v.z + v.w * v.w;
        #pragma unroll
        for (int off = 32; off; off >>= 1) s += __shfl_down(s, off, 64);
        if (lane == 0) Cn[code] = s;
    }
}

// ---------------- kernel 2: fused distance GEMM + online argmin ----------------
__global__ __launch_bounds__(256, 2) void vq_scores(const float* __restrict__ z,
                                                    const float* __restrict__ cbt,
                                                    const float* __restrict__ An,
                                                    const float* __restrict__ Cn,
                                                    float* __restrict__ ws_val,
                                                    int*   __restrict__ ws_idx) {
    __shared__ float Zs[KC][TILE_M];        // [d][token], conflict-free
    __shared__ float Cs[KC][CS_W];          // [d][swizzled code]

    const int tid = threadIdx.x;
    const int ty = tid >> 4;       // 0..15 -> token octet
    const int tx = tid & 15;       // 0..15 -> 16-code group
    const int tile  = blockIdx.x & 63;
    const int split = blockIdx.x >> 6;
    const int token0 = tile * TILE_M;
    const int code0  = split * NSPLIT;
    const float* zb = z + (size_t)(token0 >> 10) * (DD * TT) + (token0 & 1023);
    const int bofs = 16 * tx + 4 * (tx >> 1);   // swizzled read base (16B-aligned)

    float best[8];
    int   bidx[8];
    float Ai[8];
    #pragma unroll
    for (int i = 0; i < 8; ++i) {
        best[i] = FLT_INF; bidx[i] = 0;
        Ai[i] = An[token0 + ty * 8 + i];
    }

    float4 zr[4], cr[8];

    for (int ct = 0; ct < CT; ++ct) {
        const int cbase = code0 + ct * TILE_N;
        float acc[8][16];
        #pragma unroll
        for (int i = 0; i < 8; ++i)
            #pragma unroll
            for (int j = 0; j < 16; ++j) acc[i][j] = 0.f;

        // prefetch kc=0 into registers
        #pragma unroll
        for (int n = 0; n < 4; ++n) {
            int fid = n * 256 + tid;
            int k = fid >> 5, c4 = fid & 31;
            zr[n] = *(const float4*)&zb[(size_t)k * TT + c4 * 4];
        }
        #pragma unroll
        for (int n = 0; n < 8; ++n) {
            int fid = n * 256 + tid;
            int k = fid >> 6, c4 = fid & 63;
            cr[n] = *(const float4*)&cbt[(size_t)k * KK + cbase + c4 * 4];
        }

        for (int kc = 0; kc < NKC; ++kc) {
            __syncthreads();   // previous round's LDS readers done
            #pragma unroll
            for (int n = 0; n < 4; ++n) {
                int fid = n * 256 + tid;
                int k = fid >> 5, c4 = fid & 31;
                *(float4*)&Zs[k][c4 * 4] = zr[n];
            }
            #pragma unroll
            for (int n = 0; n < 8; ++n) {
                int fid = n * 256 + tid;
                int k = fid >> 6, c4 = fid & 63;
                *(float4*)&Cs[k][4 * c4 + 4 * (c4 >> 3)] = cr[n];
            }
            __syncthreads();

            if (kc + 1 < NKC) {    // prefetch next round while computing this one
                #pragma unroll
                for (int n = 0; n < 4; ++n) {
                    int fid = n * 256 + tid;
                    int k = fid >> 5, c4 = fid & 31;
                    zr[n] = *(const float4*)&zb[(size_t)((kc + 1) * KC + k) * TT + c4 * 4];
                }
                #pragma unroll
                for (int n = 0; n < 8; ++n) {
                    int fid = n * 256 + tid;
                    int k = fid >> 6, c4 = fid & 63;
                    cr[n] = *(const float4*)&cbt[(size_t)((kc + 1) * KC + k) * KK + cbase + c4 * 4];
                }
            }

            #pragma unroll 4
            for (int k = 0; k < KC; ++k) {
                float4 a0 = *(const float4*)&Zs[k][ty * 8];
                float4 a1 = *(const float4*)&Zs[k][ty * 8 + 4];
                const float4* bp = (const float4*)&Cs[k][bofs];
                float4 b0 = bp[0], b1 = bp[1], b2 = bp[2], b3 = bp[3];
                float av[8]  = {a0.x, a0.y, a0.z, a0.w, a1.x, a1.y, a1.z, a1.w};
                float bv[16] = {b0.x, b0.y, b0.z, b0.w, b1.x, b1.y, b1.z, b1.w,
                                b2.x, b2.y, b2.z, b2.w, b3.x, b3.y, b3.z, b3.w};
                #pragma unroll
                for (int i = 0; i < 8; ++i)
                    #pragma unroll
                    for (int j = 0; j < 16; ++j)
                        acc[i][j] = fmaf(av[i], bv[j], acc[i][j]);
            }
        }

        // epilogue: distance = fl(fl(A - 2B) + C), online argmin (ascending code)
        float cv[16];
        #pragma unroll
        for (int j = 0; j < 16; ++j) cv[j] = Cn[cbase + tx * 16 + j];
        #pragma unroll
        for (int i = 0; i < 8; ++i) {
            #pragma unroll
            for (int j = 0; j < 16; ++j) {
                float d1 = fmaf(-2.f, acc[i][j], Ai[i]);   // == fl(A - 2B): 2B exact
                float dist = d1 + cv[j];                    // fl(+C)
                int idx = cbase + tx * 16 + j;
                if (dist < best[i]) { best[i] = dist; bidx[i] = idx; }
            }
        }
    }

    // reduce across the 16 tx lanes (same wave, width-16 subgroups)
    #pragma unroll
    for (int off = 8; off; off >>= 1) {
        #pragma unroll
        for (int i = 0; i < 8; ++i) {
            float ov = __shfl_down(best[i], off, 16);
            int   oi = __shfl_down(bidx[i], off, 16);
            if (ov < best[i] || (ov == best[i] && oi < bidx[i])) {
                best[i] = ov; bidx[i] = oi;
            }
        }
    }
    if (tx == 0) {
        #pragma unroll
        for (int i = 0; i < 8; ++i) {
            int tok = token0 + ty * 8 + i;
            ws_val[split * BT + tok] = best[i];
            ws_idx[split * BT + tok] = bidx[i];
        }
    }
}

// ---------------- kernel 3: reduce splits -> final indices ----------------
__global__ __launch_bounds__(256) void vq_finalize(const float* __restrict__ ws_val,
                                                   const int* __restrict__ ws_idx,
                                                   int* __restrict__ fidx,
                                                   float* __restrict__ out_idx,
                                                   float* __restrict__ loss_acc) {
    int g = blockIdx.x * 256 + threadIdx.x;
    float bv = FLT_INF; int bi = 0;
    #pragma unroll
    for (int s = 0; s < SPLITS; ++s) {       // ascending code ranges: strict < keeps first
        float v = ws_val[s * BT + g];
        int  ix = ws_idx[s * BT + g];
        if (v < bv) { bv = v; bi = ix; }
    }
    fidx[g] = bi;
    out_idx[g] = (float)bi;                  // out buffer is fp32
    if (g == 0) *loss_acc = 0.f;
}

// ---------------- kernel 4: gather z_q, straight-through out, loss partial ----------------
__global__ __launch_bounds__(256) void vq_gather(const float* __restrict__ z,
                                                 const float* __restrict__ cb,
                                                 const int* __restrict__ fidx,
                                                 float* __restrict__ out,
                                                 float* __restrict__ loss_acc) {
    int e4 = blockIdx.x * 256 + threadIdx.x;     // float4 index, 524288 total
    int t4 = e4 & 255;
    int rest = e4 >> 8;
    int d = rest & 255;
    int b = rest >> 8;
    int gbase = b * 1024 + t4 * 4;

    int4 iv = *(const int4*)&fidx[gbase];
    float4 zv = *(const float4*)&z[(size_t)e4 * 4];

    float q0 = cb[(size_t)iv.x * DD + d];
    float q1 = cb[(size_t)iv.y * DD + d];
    float q2 = cb[(size_t)iv.z * DD + d];
    float q3 = cb[(size_t)iv.w * DD + d];

    float d0 = q0 - zv.x, d1 = q1 - zv.y, d2 = q2 - zv.z, d3 = q3 - zv.w;
    float4 o;                                    // replicate z + (z_q - z) rounding
    o.x = zv.x + d0; o.y = zv.y + d1; o.z = zv.z + d2; o.w = zv.w + d3;
    *(float4*)&out[(size_t)e4 * 4] = o;

    float s = d0 * d0 + d1 * d1 + d2 * d2 + d3 * d3;
    #pragma unroll
    for (int off = 32; off; off >>= 1) s += __shfl_down(s, off, 64);
    __shared__ float wsum[4];
    if ((threadIdx.x & 63) == 0) wsum[threadIdx.x >> 6] = s;
    __syncthreads();
    if (threadIdx.x == 0)
        atomicAdd(loss_acc, wsum[0] + wsum[1] + wsum[2] + wsum[3]);
}

// ---------------- kernel 5: finalize loss ----------------
__global__ void vq_loss(const float* __restrict__ loss_acc, float* __restrict__ out_loss) {
    *out_loss = 1.25f * (*loss_acc) / 2097152.f;
}

extern "C" void kernel_launch(void* const* d_in, const int* in_sizes, int n_in,
                              void* d_out, int out_size, void* d_ws, size_t ws_size,
                              hipStream_t stream) {
    const float* z  = (const float*)d_in[0];
    const float* cb = (const float*)d_in[1];
    float* out = (float*)d_out;
    float* ws  = (float*)d_ws;

    float* CbT     = ws + CBT_OFF;
    float* An      = ws + A_OFF;
    float* Cn      = ws + C_OFF;
    float* ws_val  = ws + VAL_OFF;
    int*   ws_idx  = (int*)(ws + IDX_OFF);
    int*   fidx    = (int*)(ws + FIDX_OFF);
    float* acc     = ws + ACC_OFF;

    vq_prep    <<<32 + 2048 + 2048, 256, 0, stream>>>(z, cb, An, CbT, Cn);
    vq_scores  <<<64 * SPLITS, 256, 0, stream>>>(z, CbT, An, Cn, ws_val, ws_idx);
    vq_finalize<<<BT / 256,    256, 0, stream>>>(ws_val, ws_idx, fidx, out + ZQ_SIZE, acc);
    vq_gather  <<<ZQ_SIZE / 1024, 256, 0, stream>>>(z, cb, fidx, out, acc);
    vq_loss    <<<1, 1, 0, stream>>>(acc, out + ZQ_SIZE + BT);
}

// Round 3
// 611.458 us; speedup vs baseline: 1.0401x; 1.0401x over previous
//
#include <hip/hip_runtime.h>

#define DD   256
#define TT   1024
#define BB   8
#define BT   8192
#define KK   8192
#define SPLITS 16
#define NSPLIT 512          // codes per split
#define TILE_M 128          // tokens per block
#define TILE_N 128          // codes per inner tile
#define CT     4            // NSPLIT / TILE_N
#define KC     32           // d-chunk
#define NKC    8            // DD / KC

#define ZQ_SIZE 2097152     // B*D*T

// ws layout in floats
#define CBT_OFF  0
#define A_OFF    2097152
#define C_OFF    (A_OFF + BT)
#define VAL_OFF  (C_OFF + KK)
#define IDX_OFF  (VAL_OFF + SPLITS*BT)
#define FIDX_OFF (IDX_OFF + SPLITS*BT)
#define ACC_OFF  (FIDX_OFF + BT)

#define FLT_INF 3.402823466e38f

// ---------------- kernel 1: prep = token norms + codebook transpose + code norms ----------------
__global__ __launch_bounds__(256) void vq_prep(const float* __restrict__ z,
                                               const float* __restrict__ cb,
                                               float* __restrict__ An,
                                               float* __restrict__ CbT,
                                               float* __restrict__ Cn) {
    if (blockIdx.x < 32) {
        // A[token] = sum_d z[b,d,t]^2 ; coalesced over t
        int g = blockIdx.x * 256 + threadIdx.x;      // 0..8191
        int b = g >> 10, t = g & 1023;
        const float* zp = z + (size_t)b * (DD * TT) + t;
        float s = 0.f;
        #pragma unroll 8
        for (int d = 0; d < DD; ++d) {
            float v = zp[d * TT];
            float v2 = v * v;              // match np: square rounded, then sum
            s = s + v2;
        }
        An[g] = s;
    } else if (blockIdx.x < 32 + 2048) {
        // transpose codebook: CbT[d][code] = cb[code][d]
        int fid = (blockIdx.x - 32) * 256 + threadIdx.x;   // 0..524287
        int code = fid & 8191;
        int d = (fid >> 13) * 4;                           // 0..252
        float4 v = *(const float4*)&cb[(size_t)code * DD + d];
        CbT[(size_t)(d + 0) * KK + code] = v.x;            // coalesced over code
        CbT[(size_t)(d + 1) * KK + code] = v.y;
        CbT[(size_t)(d + 2) * KK + code] = v.z;
        CbT[(size_t)(d + 3) * KK + code] = v.w;
    } else {
        // C[code] = ||codebook row||^2, one wave per code
        int code = (blockIdx.x - 2080) * 4 + (threadIdx.x >> 6);
        int lane = threadIdx.x & 63;
        float4 v = *(const float4*)&cb[(size_t)code * DD + lane * 4];
        float s = v.x * v.x + v.y * v.y + v.z * v.z + v.w * v.w;
        #pragma unroll
        for (int off = 32; off; off >>= 1) s += __shfl_down(s, off, 64);
        if (lane == 0) Cn[code] = s;
    }
}

// ---------------- kernel 2: fused distance GEMM + online argmin ----------------
// 8x8 register tile (round-1 footprint, zero spill) + conflict-free LDS layouts
// (codebook pre-transposed, so both stages are linear b128 stores) + register
// prefetch of chunk kc+1 issued before the compute phase.
__global__ __launch_bounds__(256, 3) void vq_scores(const float* __restrict__ z,
                                                    const float* __restrict__ cbt,
                                                    const float* __restrict__ An,
                                                    const float* __restrict__ Cn,
                                                    float* __restrict__ ws_val,
                                                    int*   __restrict__ ws_idx) {
    __shared__ float Zs[KC][TILE_M];        // [d][token]  : stores linear b128, reads broadcast
    __shared__ float Cs[KC][TILE_N];        // [d][code]   : stores linear b128, reads 2-way (free)

    const int tid = threadIdx.x;
    const int ty = tid >> 4;       // 0..15 -> token octet
    const int tx = tid & 15;       // 0..15 -> code octet
    const int tile  = blockIdx.x & 63;
    const int split = blockIdx.x >> 6;
    const int token0 = tile * TILE_M;
    const int code0  = split * NSPLIT;
    const float* zb = z + (size_t)(token0 >> 10) * (DD * TT) + (token0 & 1023);

    // staging indices (shared by prefetch + store)
    const int zk = tid >> 5, zc = (tid & 31) * 4;        // + n*8 rows per chunk of 256 threads
    const int ck = tid >> 5, cc = (tid & 31) * 4;

    float best[8];
    int   bidx[8];
    float Ai[8];
    #pragma unroll
    for (int i = 0; i < 8; ++i) {
        best[i] = FLT_INF; bidx[i] = 0;
        Ai[i] = An[token0 + ty * 8 + i];
    }

    float4 zr[4], cr[4];

    for (int ct = 0; ct < CT; ++ct) {
        const int cbase = code0 + ct * TILE_N;
        float acc[8][8];
        #pragma unroll
        for (int i = 0; i < 8; ++i)
            #pragma unroll
            for (int j = 0; j < 8; ++j) acc[i][j] = 0.f;

        // prefetch kc=0 into registers
        #pragma unroll
        for (int n = 0; n < 4; ++n)
            zr[n] = *(const float4*)&zb[(size_t)(n * 8 + zk) * TT + zc];
        #pragma unroll
        for (int n = 0; n < 4; ++n)
            cr[n] = *(const float4*)&cbt[(size_t)(n * 8 + ck) * KK + cbase + cc];

        for (int kc = 0; kc < NKC; ++kc) {
            __syncthreads();   // previous round's LDS readers done
            #pragma unroll
            for (int n = 0; n < 4; ++n)
                *(float4*)&Zs[n * 8 + zk][zc] = zr[n];
            #pragma unroll
            for (int n = 0; n < 4; ++n)
                *(float4*)&Cs[n * 8 + ck][cc] = cr[n];
            __syncthreads();

            if (kc + 1 < NKC) {    // issue next chunk's loads; latency hides under compute
                const int kb = (kc + 1) * KC;
                #pragma unroll
                for (int n = 0; n < 4; ++n)
                    zr[n] = *(const float4*)&zb[(size_t)(kb + n * 8 + zk) * TT + zc];
                #pragma unroll
                for (int n = 0; n < 4; ++n)
                    cr[n] = *(const float4*)&cbt[(size_t)(kb + n * 8 + ck) * KK + cbase + cc];
            }

            #pragma unroll 8
            for (int k = 0; k < KC; ++k) {
                float4 a0 = *(const float4*)&Zs[k][ty * 8];
                float4 a1 = *(const float4*)&Zs[k][ty * 8 + 4];
                float4 b0 = *(const float4*)&Cs[k][tx * 8];
                float4 b1 = *(const float4*)&Cs[k][tx * 8 + 4];
                float av[8] = {a0.x, a0.y, a0.z, a0.w, a1.x, a1.y, a1.z, a1.w};
                float bv[8] = {b0.x, b0.y, b0.z, b0.w, b1.x, b1.y, b1.z, b1.w};
                #pragma unroll
                for (int i = 0; i < 8; ++i)
                    #pragma unroll
                    for (int j = 0; j < 8; ++j)
                        acc[i][j] = fmaf(av[i], bv[j], acc[i][j]);
            }
        }

        // epilogue: distance = fl(fl(A - 2B) + C), online argmin (ascending code)
        float cv[8];
        #pragma unroll
        for (int j = 0; j < 8; ++j) cv[j] = Cn[cbase + tx * 8 + j];
        #pragma unroll
        for (int i = 0; i < 8; ++i) {
            #pragma unroll
            for (int j = 0; j < 8; ++j) {
                float d1 = fmaf(-2.f, acc[i][j], Ai[i]);   // == fl(A - 2B): 2B exact
                float dist = d1 + cv[j];                    // fl(+C)
                int idx = cbase + tx * 8 + j;
                if (dist < best[i]) { best[i] = dist; bidx[i] = idx; }
            }
        }
    }

    // reduce across the 16 tx lanes (same wave, width-16 subgroups)
    #pragma unroll
    for (int off = 8; off; off >>= 1) {
        #pragma unroll
        for (int i = 0; i < 8; ++i) {
            float ov = __shfl_down(best[i], off, 16);
            int   oi = __shfl_down(bidx[i], off, 16);
            if (ov < best[i] || (ov == best[i] && oi < bidx[i])) {
                best[i] = ov; bidx[i] = oi;
            }
        }
    }
    if (tx == 0) {
        #pragma unroll
        for (int i = 0; i < 8; ++i) {
            int tok = token0 + ty * 8 + i;
            ws_val[split * BT + tok] = best[i];
            ws_idx[split * BT + tok] = bidx[i];
        }
    }
}

// ---------------- kernel 3: reduce splits -> final indices ----------------
__global__ __launch_bounds__(256) void vq_finalize(const float* __restrict__ ws_val,
                                                   const int* __restrict__ ws_idx,
                                                   int* __restrict__ fidx,
                                                   float* __restrict__ out_idx,
                                                   float* __restrict__ loss_acc) {
    int g = blockIdx.x * 256 + threadIdx.x;
    float bv = FLT_INF; int bi = 0;
    #pragma unroll
    for (int s = 0; s < SPLITS; ++s) {       // ascending code ranges: strict < keeps first
        float v = ws_val[s * BT + g];
        int  ix = ws_idx[s * BT + g];
        if (v < bv) { bv = v; bi = ix; }
    }
    fidx[g] = bi;
    out_idx[g] = (float)bi;                  // out buffer is fp32
    if (g == 0) *loss_acc = 0.f;
}

// ---------------- kernel 4: gather z_q, straight-through out, loss partial ----------------
__global__ __launch_bounds__(256) void vq_gather(const float* __restrict__ z,
                                                 const float* __restrict__ cb,
                                                 const int* __restrict__ fidx,
                                                 float* __restrict__ out,
                                                 float* __restrict__ loss_acc) {
    int e4 = blockIdx.x * 256 + threadIdx.x;     // float4 index, 524288 total
    int t4 = e4 & 255;
    int rest = e4 >> 8;
    int d = rest & 255;
    int b = rest >> 8;
    int gbase = b * 1024 + t4 * 4;

    int4 iv = *(const int4*)&fidx[gbase];
    float4 zv = *(const float4*)&z[(size_t)e4 * 4];

    float q0 = cb[(size_t)iv.x * DD + d];
    float q1 = cb[(size_t)iv.y * DD + d];
    float q2 = cb[(size_t)iv.z * DD + d];
    float q3 = cb[(size_t)iv.w * DD + d];

    float d0 = q0 - zv.x, d1 = q1 - zv.y, d2 = q2 - zv.z, d3 = q3 - zv.w;
    float4 o;                                    // replicate z + (z_q - z) rounding
    o.x = zv.x + d0; o.y = zv.y + d1; o.z = zv.z + d2; o.w = zv.w + d3;
    *(float4*)&out[(size_t)e4 * 4] = o;

    float s = d0 * d0 + d1 * d1 + d2 * d2 + d3 * d3;
    #pragma unroll
    for (int off = 32; off; off >>= 1) s += __shfl_down(s, off, 64);
    __shared__ float wsum[4];
    if ((threadIdx.x & 63) == 0) wsum[threadIdx.x >> 6] = s;
    __syncthreads();
    if (threadIdx.x == 0)
        atomicAdd(loss_acc, wsum[0] + wsum[1] + wsum[2] + wsum[3]);
}

// ---------------- kernel 5: finalize loss ----------------
__global__ void vq_loss(const float* __restrict__ loss_acc, float* __restrict__ out_loss) {
    *out_loss = 1.25f * (*loss_acc) / 2097152.f;
}

extern "C" void kernel_launch(void* const* d_in, const int* in_sizes, int n_in,
                              void* d_out, int out_size, void* d_ws, size_t ws_size,
                              hipStream_t stream) {
    const float* z  = (const float*)d_in[0];
    const float* cb = (const float*)d_in[1];
    float* out = (float*)d_out;
    float* ws  = (float*)d_ws;

    float* CbT     = ws + CBT_OFF;
    float* An      = ws + A_OFF;
    float* Cn      = ws + C_OFF;
    float* ws_val  = ws + VAL_OFF;
    int*   ws_idx  = (int*)(ws + IDX_OFF);
    int*   fidx    = (int*)(ws + FIDX_OFF);
    float* acc     = ws + ACC_OFF;

    vq_prep    <<<32 + 2048 + 2048, 256, 0, stream>>>(z, cb, An, CbT, Cn);
    vq_scores  <<<64 * SPLITS, 256, 0, stream>>>(z, CbT, An, Cn, ws_val, ws_idx);
    vq_finalize<<<BT / 256,    256, 0, stream>>>(ws_val, ws_idx, fidx, out + ZQ_SIZE, acc);
    vq_gather  <<<ZQ_SIZE / 1024, 256, 0, stream>>>(z, cb, fidx, out, acc);
    vq_loss    <<<1, 1, 0, stream>>>(acc, out + ZQ_SIZE + BT);
}

// Round 4
// 409.977 us; speedup vs baseline: 1.5512x; 1.4914x over previous
//
#include <hip/hip_runtime.h>

#define DD   256
#define TT   1024
#define BT   8192
#define KK   8192
#define ZQ_SIZE 2097152

#define FLT_INF 3.402823466e38f

typedef __attribute__((ext_vector_type(8))) short short8;
typedef __attribute__((ext_vector_type(4))) float f32x4;

// ws layout (bytes)
#define ASP_B   0u           // Asplit: 8192 x 768 bf16 (h|m|l)  = 12582912 B
#define BSP_B   12582912u    // Bsplit: same
#define AN_B    25165824u    // An: 8192 f32
#define CN_B    25198592u    // Cn: 8192 f32
#define KEY_B   25231360u    // keys: 8192 u64
#define FIDX_B  25296896u    // fidx: 8192 i32
#define ACC_B   25329664u    // loss acc: 1 f32

static __device__ __forceinline__ unsigned short f2bf(float x) {  // RNE fp32->bf16
    unsigned int u = __float_as_uint(x);
    return (unsigned short)((u + 0x7FFF + ((u >> 16) & 1)) >> 16);
}
static __device__ __forceinline__ float bf2f(unsigned short h) {
    return __uint_as_float(((unsigned int)h) << 16);
}
// exact 3-term split: x == h + m + l (each difference exact in fp32)
static __device__ __forceinline__ void split3(float x, unsigned short& h,
                                              unsigned short& m, unsigned short& l) {
    h = f2bf(x);
    float r1 = x - bf2f(h);
    m = f2bf(r1);
    l = f2bf(r1 - bf2f(m));
}

static __device__ __forceinline__ void gld16(const void* g, const void* l) {
    __builtin_amdgcn_global_load_lds(
        (const __attribute__((address_space(1))) unsigned int*)g,
        (__attribute__((address_space(3))) unsigned int*)l, 16, 0, 0);
}

// ---------------- kernel 1: An + keys init | Bsplit | Cn ----------------
__global__ __launch_bounds__(256) void vq_prep(const float* __restrict__ z,
                                               const float* __restrict__ cb,
                                               float* __restrict__ An,
                                               unsigned short* __restrict__ Bsp,
                                               float* __restrict__ Cn,
                                               unsigned long long* __restrict__ keys,
                                               float* __restrict__ lacc) {
    if (blockIdx.x < 32) {
        int g = blockIdx.x * 256 + threadIdx.x;      // 0..8191 token
        int b = g >> 10, t = g & 1023;
        const float* zp = z + (size_t)b * (DD * TT) + t;
        float s = 0.f;
        #pragma unroll 8
        for (int d = 0; d < DD; ++d) {
            float v = zp[d * TT];
            float v2 = v * v;
            s = s + v2;
        }
        An[g] = s;
        keys[g] = ~0ull;
        if (g == 0) *lacc = 0.f;
    } else if (blockIdx.x < 32 + 2048) {
        // Bsplit: cb row-major -> [code][h(256)|m(256)|l(256)] bf16
        int g = (blockIdx.x - 32) * 256 + threadIdx.x;   // 0..524287
        int code = g >> 6, d4 = (g & 63) * 4;
        float4 v = *(const float4*)&cb[(size_t)code * DD + d4];
        unsigned short h[4], m[4], l[4];
        split3(v.x, h[0], m[0], l[0]);
        split3(v.y, h[1], m[1], l[1]);
        split3(v.z, h[2], m[2], l[2]);
        split3(v.w, h[3], m[3], l[3]);
        unsigned short* row = Bsp + (size_t)code * 768 + d4;
        *(ushort4*)&row[0]   = make_ushort4(h[0], h[1], h[2], h[3]);
        *(ushort4*)&row[256] = make_ushort4(m[0], m[1], m[2], m[3]);
        *(ushort4*)&row[512] = make_ushort4(l[0], l[1], l[2], l[3]);
    } else {
        int code = (blockIdx.x - 2080) * 4 + (threadIdx.x >> 6);
        int lane = threadIdx.x & 63;
        float4 v = *(const float4*)&cb[(size_t)code * DD + lane * 4];
        float s = v.x * v.x + v.y * v.y + v.z * v.z + v.w * v.w;
        #pragma unroll
        for (int off = 32; off; off >>= 1) s += __shfl_down(s, off, 64);
        if (lane == 0) Cn[code] = s;
    }
}

// ---------------- kernel 2: Asplit via LDS transpose ----------------
__global__ __launch_bounds__(256) void vq_prep_a(const float* __restrict__ z,
                                                 unsigned short* __restrict__ Asp) {
    __shared__ float T[64][257];
    int b = blockIdx.x >> 4;
    int t0 = (blockIdx.x & 15) * 64;
    int tid = threadIdx.x;
    #pragma unroll
    for (int it = 0; it < 16; ++it) {
        int d = it * 16 + (tid >> 4);
        int t4 = (tid & 15) * 4;
        float4 v = *(const float4*)&z[(size_t)b * (DD * TT) + (size_t)d * TT + t0 + t4];
        T[t4 + 0][d] = v.x; T[t4 + 1][d] = v.y; T[t4 + 2][d] = v.z; T[t4 + 3][d] = v.w;
    }
    __syncthreads();
    int r = tid >> 2, q = tid & 3;
    int token = b * 1024 + t0 + r;
    unsigned short* arow = Asp + (size_t)token * 768;
    #pragma unroll
    for (int dd = 0; dd < 16; ++dd) {
        int d = dd * 16 + q * 4;
        unsigned short h[4], m[4], l[4];
        #pragma unroll
        for (int c = 0; c < 4; ++c) split3(T[r][d + c], h[c], m[c], l[c]);
        *(ushort4*)&arow[d]       = make_ushort4(h[0], h[1], h[2], h[3]);
        *(ushort4*)&arow[256 + d] = make_ushort4(m[0], m[1], m[2], m[3]);
        *(ushort4*)&arow[512 + d] = make_ushort4(l[0], l[1], l[2], l[3]);
    }
}

// ---------------- kernel 3: bf16x3 MFMA distance GEMM + fused argmin ----------------
// K = 6 chunk-pairs x 256: (h,h')(h,m')(m,h')(h,l')(l,h')(m,m')  -> exact to ~2^-27 rel
__global__ __launch_bounds__(256) void vq_scores(const unsigned short* __restrict__ Asp,
                                                 const unsigned short* __restrict__ Bsp,
                                                 const float* __restrict__ An,
                                                 const float* __restrict__ Cn,
                                                 unsigned long long* __restrict__ keys) {
    // [row][64k] bf16, XOR slot swizzle: physical 16B-slot p = s ^ (row&7)
    __shared__ __attribute__((aligned(16))) unsigned short At[128 * 64];
    __shared__ __attribute__((aligned(16))) unsigned short Bt[128 * 64];

    // 8x8 block-group swizzle for L2 locality
    int bid = blockIdx.x;
    int g = bid >> 6, sl = bid & 63;
    int mt = (g >> 3) * 8 + (sl >> 3);
    int nt = (g & 7) * 8 + (sl & 7);
    const int token0 = mt * 128, code0 = nt * 128;

    const int wid = threadIdx.x >> 6, lane = threadIdx.x & 63;
    const int m0w = (wid >> 1) * 64, n0w = (wid & 1) * 64;

    // staging geometry: wave wid stages rows [wid*32, wid*32+32), 4 insts of 8 rows
    const int srl = lane >> 3;                    // row-within-8
    const int slot = lane & 7;                    // physical 16B slot (LDS contiguous)
    const int swrow = (srl & 7);                  // row&7 for the XOR (n*8 keeps it)
    const int gslot = slot ^ swrow;               // logical k-slot fetched by this lane
    const size_t arow0 = (size_t)(token0 + wid * 32 + srl) * 768;
    const size_t brow0 = (size_t)(code0 + wid * 32 + srl) * 768;

    f32x4 acc[4][4];
    #pragma unroll
    for (int i = 0; i < 4; ++i)
        #pragma unroll
        for (int j = 0; j < 4; ++j) acc[i][j] = (f32x4){0.f, 0.f, 0.f, 0.f};

    const int aSC[6] = {0, 0, 1, 0, 2, 1};
    const int bSC[6] = {0, 1, 0, 2, 0, 1};

    for (int c = 0; c < 6; ++c) {
        const int ka = aSC[c] * 256, kb = bSC[c] * 256;
        for (int kk = 0; kk < 4; ++kk) {          // 4 x BK=64
            const int kca = ka + kk * 64 + gslot * 8;
            const int kcb = kb + kk * 64 + gslot * 8;
            __syncthreads();                      // previous chunk's readers done
            #pragma unroll
            for (int n = 0; n < 4; ++n) {
                gld16(Asp + arow0 + (size_t)n * 8 * 768 + kca,
                      &At[(wid * 32 + n * 8) * 64]);
                gld16(Bsp + brow0 + (size_t)n * 8 * 768 + kcb,
                      &Bt[(wid * 32 + n * 8) * 64]);
            }
            __syncthreads();                      // vmcnt(0) drained by compiler

            #pragma unroll
            for (int h = 0; h < 2; ++h) {
                short8 af[4], bf[4];
                const int s0 = h * 4 + (lane >> 4);   // logical slot of this frag
                #pragma unroll
                for (int i = 0; i < 4; ++i) {
                    int row = m0w + i * 16 + (lane & 15);
                    af[i] = *(const short8*)&At[row * 64 + ((s0 ^ (row & 7)) * 8)];
                }
                #pragma unroll
                for (int j = 0; j < 4; ++j) {
                    int row = n0w + j * 16 + (lane & 15);
                    bf[j] = *(const short8*)&Bt[row * 64 + ((s0 ^ (row & 7)) * 8)];
                }
                #pragma unroll
                for (int i = 0; i < 4; ++i)
                    #pragma unroll
                    for (int j = 0; j < 4; ++j)
                        acc[i][j] = __builtin_amdgcn_mfma_f32_16x16x32_bf16(
                            af[i], bf[j], acc[i][j], 0, 0, 0);
            }
        }
    }

    // epilogue: dist = fl(fl(A - 2B) + C); argmin; C/D layout col=lane&15, row=quad*4+reg
    const int quad = lane >> 4, col = lane & 15;
    float cn[4]; int cidx[4];
    #pragma unroll
    for (int j = 0; j < 4; ++j) {
        cidx[j] = code0 + n0w + j * 16 + col;
        cn[j] = Cn[cidx[j]];
    }
    #pragma unroll
    for (int i = 0; i < 4; ++i) {
        #pragma unroll
        for (int r = 0; r < 4; ++r) {
            int token = token0 + m0w + i * 16 + quad * 4 + r;
            float Ai = An[token];
            float bv = FLT_INF; int bi = 0;
            #pragma unroll
            for (int j = 0; j < 4; ++j) {
                float d1 = fmaf(-2.f, acc[i][j][r], Ai);   // fl(A-2B): 2B exact
                float dist = d1 + cn[j];                    // fl(+C)
                if (dist < bv) { bv = dist; bi = cidx[j]; }
            }
            #pragma unroll
            for (int off = 8; off; off >>= 1) {
                float ov = __shfl_down(bv, off, 16);
                int   oi = __shfl_down(bi, off, 16);
                if (ov < bv || (ov == bv && oi < bi)) { bv = ov; bi = oi; }
            }
            if (col == 0) {
                unsigned long long key =
                    ((unsigned long long)__float_as_uint(bv) << 32) | (unsigned)bi;
                atomicMin(&keys[token], key);
            }
        }
    }
}

// ---------------- kernel 4: keys -> indices ----------------
__global__ __launch_bounds__(256) void vq_finalize(const unsigned long long* __restrict__ keys,
                                                   int* __restrict__ fidx,
                                                   float* __restrict__ out_idx) {
    int gi = blockIdx.x * 256 + threadIdx.x;
    int bi = (int)(unsigned)(keys[gi] & 0xffffffffu);
    fidx[gi] = bi;
    out_idx[gi] = (float)bi;
}

// ---------------- kernel 5: gather z_q, straight-through out, loss partial ----------------
__global__ __launch_bounds__(256) void vq_gather(const float* __restrict__ z,
                                                 const float* __restrict__ cb,
                                                 const int* __restrict__ fidx,
                                                 float* __restrict__ out,
                                                 float* __restrict__ loss_acc) {
    int e4 = blockIdx.x * 256 + threadIdx.x;     // float4 index, 524288 total
    int t4 = e4 & 255;
    int rest = e4 >> 8;
    int d = rest & 255;
    int b = rest >> 8;
    int gbase = b * 1024 + t4 * 4;

    int4 iv = *(const int4*)&fidx[gbase];
    float4 zv = *(const float4*)&z[(size_t)e4 * 4];

    float q0 = cb[(size_t)iv.x * DD + d];
    float q1 = cb[(size_t)iv.y * DD + d];
    float q2 = cb[(size_t)iv.z * DD + d];
    float q3 = cb[(size_t)iv.w * DD + d];

    float d0 = q0 - zv.x, d1 = q1 - zv.y, d2 = q2 - zv.z, d3 = q3 - zv.w;
    float4 o;                                    // replicate z + (z_q - z) rounding
    o.x = zv.x + d0; o.y = zv.y + d1; o.z = zv.z + d2; o.w = zv.w + d3;
    *(float4*)&out[(size_t)e4 * 4] = o;

    float s = d0 * d0 + d1 * d1 + d2 * d2 + d3 * d3;
    #pragma unroll
    for (int off = 32; off; off >>= 1) s += __shfl_down(s, off, 64);
    __shared__ float wsum[4];
    if ((threadIdx.x & 63) == 0) wsum[threadIdx.x >> 6] = s;
    __syncthreads();
    if (threadIdx.x == 0)
        atomicAdd(loss_acc, wsum[0] + wsum[1] + wsum[2] + wsum[3]);
}

// ---------------- kernel 6: finalize loss ----------------
__global__ void vq_loss(const float* __restrict__ loss_acc, float* __restrict__ out_loss) {
    *out_loss = 1.25f * (*loss_acc) / 2097152.f;
}

extern "C" void kernel_launch(void* const* d_in, const int* in_sizes, int n_in,
                              void* d_out, int out_size, void* d_ws, size_t ws_size,
                              hipStream_t stream) {
    const float* z  = (const float*)d_in[0];
    const float* cb = (const float*)d_in[1];
    float* out = (float*)d_out;
    char*  w   = (char*)d_ws;

    unsigned short* Asp = (unsigned short*)(w + ASP_B);
    unsigned short* Bsp = (unsigned short*)(w + BSP_B);
    float* An = (float*)(w + AN_B);
    float* Cn = (float*)(w + CN_B);
    unsigned long long* keys = (unsigned long long*)(w + KEY_B);
    int*   fidx = (int*)(w + FIDX_B);
    float* lacc = (float*)(w + ACC_B);

    vq_prep    <<<32 + 2048 + 2048, 256, 0, stream>>>(z, cb, An, Bsp, Cn, keys, lacc);
    vq_prep_a  <<<128,  256, 0, stream>>>(z, Asp);
    vq_scores  <<<4096, 256, 0, stream>>>(Asp, Bsp, An, Cn, keys);
    vq_finalize<<<32,   256, 0, stream>>>(keys, fidx, out + ZQ_SIZE);
    vq_gather  <<<ZQ_SIZE / 1024, 256, 0, stream>>>(z, cb, fidx, out, lacc);
    vq_loss    <<<1, 1, 0, stream>>>(lacc, out + ZQ_SIZE + BT);
}

// Round 5
// 321.009 us; speedup vs baseline: 1.9812x; 1.2772x over previous
//
#include <hip/hip_runtime.h>

#define DD   256
#define TT   1024
#define BT   8192
#define KK   8192
#define ZQ_SIZE 2097152

#define FLT_INF 3.402823466e38f

typedef __attribute__((ext_vector_type(8))) short short8;
typedef __attribute__((ext_vector_type(4))) float f32x4;

// ws layout (bytes)
#define ASP_B   0u           // Asplit: 8192 x 768 bf16 (h|m|l)  = 12582912 B
#define BSP_B   12582912u    // Bsplit: same
#define AN_B    25165824u    // An: 8192 f32
#define CN_B    25198592u    // Cn: 8192 f32
#define KEY_B   25231360u    // keys: 8192 u64
#define ACC_B   25296896u    // loss acc: 1 f32

static __device__ __forceinline__ unsigned short f2bf(float x) {  // RNE fp32->bf16
    unsigned int u = __float_as_uint(x);
    return (unsigned short)((u + 0x7FFF + ((u >> 16) & 1)) >> 16);
}
static __device__ __forceinline__ float bf2f(unsigned short h) {
    return __uint_as_float(((unsigned int)h) << 16);
}
// exact 3-term split: x == h + m + l (each difference exact in fp32)
static __device__ __forceinline__ void split3(float x, unsigned short& h,
                                              unsigned short& m, unsigned short& l) {
    h = f2bf(x);
    float r1 = x - bf2f(h);
    m = f2bf(r1);
    l = f2bf(r1 - bf2f(m));
}

static __device__ __forceinline__ void gld16(const void* g, const void* l) {
    __builtin_amdgcn_global_load_lds(
        (const __attribute__((address_space(1))) unsigned int*)g,
        (__attribute__((address_space(3))) unsigned int*)l, 16, 0, 0);
}

// ---------------- kernel 1: fused prep ----------------
// blocks 0..31:      An (token norms) + keys init + lacc init
// blocks 32..2079:   Bsplit + Cn
// blocks 2080..2207: Asplit (via LDS transpose)
__global__ __launch_bounds__(256) void vq_prep(const float* __restrict__ z,
                                               const float* __restrict__ cb,
                                               float* __restrict__ An,
                                               unsigned short* __restrict__ Asp,
                                               unsigned short* __restrict__ Bsp,
                                               float* __restrict__ Cn,
                                               unsigned long long* __restrict__ keys,
                                               float* __restrict__ lacc) {
    __shared__ float T[64][257];
    int tid = threadIdx.x;
    if (blockIdx.x < 32) {
        int g = blockIdx.x * 256 + tid;              // 0..8191 token
        int b = g >> 10, t = g & 1023;
        const float* zp = z + (size_t)b * (DD * TT) + t;
        float s = 0.f;
        #pragma unroll 8
        for (int d = 0; d < DD; ++d) {
            float v = zp[d * TT];
            float v2 = v * v;
            s = s + v2;
        }
        An[g] = s;
        keys[g] = ~0ull;
        if (g == 0) *lacc = 0.f;
    } else if (blockIdx.x < 32 + 2048) {
        // Bsplit: cb row-major -> [code][h(256)|m(256)|l(256)] bf16 ; Cn fused
        int g = (blockIdx.x - 32) * 256 + tid;       // 0..524287
        int code = g >> 6, d4 = (g & 63) * 4;
        float4 v = *(const float4*)&cb[(size_t)code * DD + d4];
        unsigned short h[4], m[4], l[4];
        split3(v.x, h[0], m[0], l[0]);
        split3(v.y, h[1], m[1], l[1]);
        split3(v.z, h[2], m[2], l[2]);
        split3(v.w, h[3], m[3], l[3]);
        unsigned short* row = Bsp + (size_t)code * 768 + d4;
        *(ushort4*)&row[0]   = make_ushort4(h[0], h[1], h[2], h[3]);
        *(ushort4*)&row[256] = make_ushort4(m[0], m[1], m[2], m[3]);
        *(ushort4*)&row[512] = make_ushort4(l[0], l[1], l[2], l[3]);
        float s = v.x * v.x + v.y * v.y + v.z * v.z + v.w * v.w;
        #pragma unroll
        for (int off = 32; off; off >>= 1) s += __shfl_down(s, off, 64);
        if ((tid & 63) == 0) Cn[code] = s;
    } else {
        // Asplit via LDS transpose: z[b,d,t] -> Asp[token][h|m|l]
        int blk = blockIdx.x - 2080;                 // 0..127
        int b = blk >> 4;
        int t0 = (blk & 15) * 64;
        #pragma unroll
        for (int it = 0; it < 16; ++it) {
            int d = it * 16 + (tid >> 4);
            int t4 = (tid & 15) * 4;
            float4 v = *(const float4*)&z[(size_t)b * (DD * TT) + (size_t)d * TT + t0 + t4];
            T[t4 + 0][d] = v.x; T[t4 + 1][d] = v.y; T[t4 + 2][d] = v.z; T[t4 + 3][d] = v.w;
        }
        __syncthreads();
        int r = tid >> 2, q = tid & 3;
        int token = b * 1024 + t0 + r;
        unsigned short* arow = Asp + (size_t)token * 768;
        #pragma unroll
        for (int dd = 0; dd < 16; ++dd) {
            int d = dd * 16 + q * 4;
            unsigned short h[4], m[4], l[4];
            #pragma unroll
            for (int c = 0; c < 4; ++c) split3(T[r][d + c], h[c], m[c], l[c]);
            *(ushort4*)&arow[d]       = make_ushort4(h[0], h[1], h[2], h[3]);
            *(ushort4*)&arow[256 + d] = make_ushort4(m[0], m[1], m[2], m[3]);
            *(ushort4*)&arow[512 + d] = make_ushort4(l[0], l[1], l[2], l[3]);
        }
    }
}

// ---------------- kernel 2: bf16x3 MFMA distance GEMM + fused argmin ----------------
// 256x256 block tile, 16 waves of 64x64, BK=64, double-buffered 2x64 KB LDS.
// K = 6 chunk-pairs x 256: (h,h')(h,m')(m,h')(h,l')(l,h')(m,m')
// aSC = {0,0,1,0,2,1} packed 0x120100 ; bSC = {0,1,0,2,0,1} packed 0x102010
__global__ __launch_bounds__(1024, 4) void vq_scores(const unsigned short* __restrict__ Asp,
                                                     const unsigned short* __restrict__ Bsp,
                                                     const float* __restrict__ An,
                                                     const float* __restrict__ Cn,
                                                     unsigned long long* __restrict__ keys) {
    // [buf][ A(256x64) | B(256x64) ] bf16, XOR slot swizzle p = s ^ (row&7)
    __shared__ __attribute__((aligned(16))) unsigned short lds[2][32768];

    // 8x8 block-group swizzle over the 32x32 tile grid
    int bid = blockIdx.x;
    int g = bid >> 6, sl = bid & 63;
    int mt = (g >> 2) * 8 + (sl >> 3);
    int nt = (g & 3) * 8 + (sl & 7);
    const int token0 = mt * 256, code0 = nt * 256;

    const int wid = threadIdx.x >> 6, lane = threadIdx.x & 63;
    const int m0w = (wid >> 2) * 64, n0w = (wid & 3) * 64;

    // staging: wave wid loads A rows [wid*16, wid*16+16) and same B rows
    const int srl = lane >> 3;                    // row-within-8
    const int gslot = (lane & 7) ^ (srl & 7);     // logical k-slot this lane fetches
    const size_t arow = (size_t)(token0 + wid * 16 + srl) * 768 + gslot * 8;
    const size_t brow = (size_t)(code0 + wid * 16 + srl) * 768 + gslot * 8;
    const int ldsrow = (wid * 16) * 64;

    f32x4 acc[4][4];
    #pragma unroll
    for (int i = 0; i < 4; ++i)
        #pragma unroll
        for (int j = 0; j < 4; ++j) acc[i][j] = (f32x4){0.f, 0.f, 0.f, 0.f};

    // prologue: stage chunk 0 into buf 0
    {
        #pragma unroll
        for (int n = 0; n < 2; ++n) {
            gld16(Asp + arow + (size_t)(n * 8) * 768, &lds[0][ldsrow + n * 8 * 64]);
            gld16(Bsp + brow + (size_t)(n * 8) * 768, &lds[0][16384 + ldsrow + n * 8 * 64]);
        }
    }

    for (int t = 0; t < 24; ++t) {
        __syncthreads();   // drains buf[t&1] loads (vmcnt0); prev readers done
        if (t < 23) {      // prefetch chunk t+1 into the other buffer
            int c = (t + 1) >> 2, kk = (t + 1) & 3;
            int ka = ((0x120100 >> (c * 4)) & 15) * 256 + kk * 64;
            int kb = ((0x102010 >> (c * 4)) & 15) * 256 + kk * 64;
            int p = (t + 1) & 1;
            #pragma unroll
            for (int n = 0; n < 2; ++n) {
                gld16(Asp + arow + (size_t)(n * 8) * 768 + ka,
                      &lds[p][ldsrow + n * 8 * 64]);
                gld16(Bsp + brow + (size_t)(n * 8) * 768 + kb,
                      &lds[p][16384 + ldsrow + n * 8 * 64]);
            }
        }
        const unsigned short* A = &lds[t & 1][0];
        const unsigned short* B = &lds[t & 1][16384];

        #pragma unroll
        for (int h = 0; h < 2; ++h) {
            short8 af[4], bf[4];
            const int s0 = h * 4 + (lane >> 4);   // logical slot of this frag
            #pragma unroll
            for (int i = 0; i < 4; ++i) {
                int row = m0w + i * 16 + (lane & 15);
                af[i] = *(const short8*)&A[row * 64 + ((s0 ^ (row & 7)) * 8)];
            }
            #pragma unroll
            for (int j = 0; j < 4; ++j) {
                int row = n0w + j * 16 + (lane & 15);
                bf[j] = *(const short8*)&B[row * 64 + ((s0 ^ (row & 7)) * 8)];
            }
            #pragma unroll
            for (int i = 0; i < 4; ++i)
                #pragma unroll
                for (int j = 0; j < 4; ++j)
                    acc[i][j] = __builtin_amdgcn_mfma_f32_16x16x32_bf16(
                        af[i], bf[j], acc[i][j], 0, 0, 0);
        }
    }

    // epilogue: dist = fl(fl(A - 2B) + C); argmin; C/D layout col=lane&15, row=quad*4+reg
    const int quad = lane >> 4, col = lane & 15;
    float cn[4]; int cidx[4];
    #pragma unroll
    for (int j = 0; j < 4; ++j) {
        cidx[j] = code0 + n0w + j * 16 + col;
        cn[j] = Cn[cidx[j]];
    }
    #pragma unroll
    for (int i = 0; i < 4; ++i) {
        #pragma unroll
        for (int r = 0; r < 4; ++r) {
            int token = token0 + m0w + i * 16 + quad * 4 + r;
            float Ai = An[token];
            float bv = FLT_INF; int bi = 0;
            #pragma unroll
            for (int j = 0; j < 4; ++j) {
                float d1 = fmaf(-2.f, acc[i][j][r], Ai);   // fl(A-2B): 2B exact
                float dist = d1 + cn[j];                    // fl(+C)
                if (dist < bv) { bv = dist; bi = cidx[j]; }
            }
            #pragma unroll
            for (int off = 8; off; off >>= 1) {
                float ov = __shfl_down(bv, off, 16);
                int   oi = __shfl_down(bi, off, 16);
                if (ov < bv || (ov == bv && oi < bi)) { bv = ov; bi = oi; }
            }
            if (col == 0) {
                unsigned long long key =
                    ((unsigned long long)__float_as_uint(bv) << 32) | (unsigned)bi;
                atomicMin(&keys[token], key);
            }
        }
    }
}

// ---------------- kernel 3: gather z_q + straight-through out + indices + loss ----------------
__global__ __launch_bounds__(256) void vq_gather(const float* __restrict__ z,
                                                 const float* __restrict__ cb,
                                                 const unsigned long long* __restrict__ keys,
                                                 float* __restrict__ out,
                                                 float* __restrict__ out_idx,
                                                 float* __restrict__ loss_acc) {
    int e4 = blockIdx.x * 256 + threadIdx.x;     // float4 index, 524288 total
    int t4 = e4 & 255;
    int rest = e4 >> 8;
    int d = rest & 255;
    int b = rest >> 8;
    int gbase = b * 1024 + t4 * 4;

    const int* klo = (const int*)keys;           // low word of each u64 key = index
    int i0 = klo[(size_t)(gbase + 0) * 2];
    int i1 = klo[(size_t)(gbase + 1) * 2];
    int i2 = klo[(size_t)(gbase + 2) * 2];
    int i3 = klo[(size_t)(gbase + 3) * 2];
    if (d == 0) {
        out_idx[gbase + 0] = (float)i0;
        out_idx[gbase + 1] = (float)i1;
        out_idx[gbase + 2] = (float)i2;
        out_idx[gbase + 3] = (float)i3;
    }

    float4 zv = *(const float4*)&z[(size_t)e4 * 4];
    float q0 = cb[(size_t)i0 * DD + d];
    float q1 = cb[(size_t)i1 * DD + d];
    float q2 = cb[(size_t)i2 * DD + d];
    float q3 = cb[(size_t)i3 * DD + d];

    float d0 = q0 - zv.x, d1 = q1 - zv.y, d2 = q2 - zv.z, d3 = q3 - zv.w;
    float4 o;                                    // replicate z + (z_q - z) rounding
    o.x = zv.x + d0; o.y = zv.y + d1; o.z = zv.z + d2; o.w = zv.w + d3;
    *(float4*)&out[(size_t)e4 * 4] = o;

    float s = d0 * d0 + d1 * d1 + d2 * d2 + d3 * d3;
    #pragma unroll
    for (int off = 32; off; off >>= 1) s += __shfl_down(s, off, 64);
    __shared__ float wsum[4];
    if ((threadIdx.x & 63) == 0) wsum[threadIdx.x >> 6] = s;
    __syncthreads();
    if (threadIdx.x == 0)
        atomicAdd(loss_acc, wsum[0] + wsum[1] + wsum[2] + wsum[3]);
}

// ---------------- kernel 4: finalize loss ----------------
__global__ void vq_loss(const float* __restrict__ loss_acc, float* __restrict__ out_loss) {
    *out_loss = 1.25f * (*loss_acc) / 2097152.f;
}

extern "C" void kernel_launch(void* const* d_in, const int* in_sizes, int n_in,
                              void* d_out, int out_size, void* d_ws, size_t ws_size,
                              hipStream_t stream) {
    const float* z  = (const float*)d_in[0];
    const float* cb = (const float*)d_in[1];
    float* out = (float*)d_out;
    char*  w   = (char*)d_ws;

    unsigned short* Asp = (unsigned short*)(w + ASP_B);
    unsigned short* Bsp = (unsigned short*)(w + BSP_B);
    float* An = (float*)(w + AN_B);
    float* Cn = (float*)(w + CN_B);
    unsigned long long* keys = (unsigned long long*)(w + KEY_B);
    float* lacc = (float*)(w + ACC_B);

    vq_prep   <<<32 + 2048 + 128, 256, 0, stream>>>(z, cb, An, Asp, Bsp, Cn, keys, lacc);
    vq_scores <<<1024, 1024, 0, stream>>>(Asp, Bsp, An, Cn, keys);
    vq_gather <<<ZQ_SIZE / 1024, 256, 0, stream>>>(z, cb, keys, out, out + ZQ_SIZE, lacc);
    vq_loss   <<<1, 1, 0, stream>>>(lacc, out + ZQ_SIZE + BT);
}